// Round 3
// baseline (287.961 us; speedup 1.0000x reference)
//
#include <hip/hip_runtime.h>
#include <hip/hip_cooperative_groups.h>
#include <math.h>

namespace cg = cooperative_groups;

#define SEQ   32768
#define DENC  200
#define NH    8192
#define NBLK  1024
#define TPB   256
#define WROWS (NH / NBLK)      // 8 W-rows per block
#define SROWS (SEQ / NBLK)     // 32 enc rows per block
#define SROWS_PW (SROWS / 4)   // 8 per wave
#define NRED  50               // blocks reducing v columns (4 each)

__device__ __forceinline__ float wave_sum(float x) {
    #pragma unroll
    for (int off = 32; off; off >>= 1) x += __shfl_xor(x, off, 64);
    return x;
}
__device__ __forceinline__ double wave_sum_d(double x) {
    #pragma unroll
    for (int off = 32; off; off >>= 1) x += __shfl_xor(x, off, 64);
    return x;
}

__global__ __launch_bounds__(TPB) void fused_attn(
    const float* __restrict__ W, const float* __restrict__ hidden,
    const float* __restrict__ bias, const float* __restrict__ enc,
    float* __restrict__ out,
    float* __restrict__ vpart,    // [NBLK][DENC]
    float* __restrict__ cpart,    // [NBLK]
    float* __restrict__ vfin,     // [DENC]
    float* __restrict__ cfin,     // [1]
    double* __restrict__ wsum)    // [NBLK]
{
    cg::grid_group grid = cg::this_grid();
    __shared__ float  v_lds[DENC];
    __shared__ float  c_lds;
    __shared__ double p_lds[SROWS];
    __shared__ double s_lds[4];
    __shared__ double inv_lds;

    const int t = threadIdx.x, b = blockIdx.x;
    const int lane = t & 63, wid = t >> 6;

    // ---- Phase 1: per-block W-row partials + bias partial ----
    {
        const int h0 = b * WROWS;
        if (t < DENC) {
            float acc = 0.f;
            #pragma unroll
            for (int i = 0; i < WROWS; ++i)
                acc = fmaf(W[(size_t)(h0 + i) * DENC + t], hidden[h0 + i], acc);
            vpart[b * DENC + t] = acc;
        }
        if (wid == 0) {
            float cp = (lane < WROWS) ? bias[h0 + lane] * hidden[h0 + lane] : 0.f;
            cp = wave_sum(cp);
            if (lane == 0) cpart[b] = cp;
        }
    }
    grid.sync();

    // ---- Phase 2: reduce partials (blocks 0..49: v columns; block 50: c) ----
    if (b < NRED) {
        const int d = b * 4 + wid;            // one column per wave
        float a = 0.f;
        #pragma unroll
        for (int k = 0; k < NBLK / 64; ++k)
            a += vpart[(size_t)(lane + k * 64) * DENC + d];
        a = wave_sum(a);
        if (lane == 0) vfin[d] = a;
    } else if (b == NRED && wid == 0) {
        float a = 0.f;
        #pragma unroll
        for (int k = 0; k < NBLK / 64; ++k)
            a += cpart[lane + k * 64];
        a = wave_sum(a);
        if (lane == 0) cfin[0] = a;
    }
    grid.sync();

    // ---- Phase 3: energies + exp(double) + per-block sum ----
    if (t < DENC) v_lds[t] = vfin[t];
    if (t == 0)  c_lds = cfin[0];
    __syncthreads();

    float4 v4 = make_float4(0.f, 0.f, 0.f, 0.f);
    if (lane < 50) v4 = *(const float4*)(v_lds + lane * 4);
    const float c = c_lds;

    {
        double acc = 0.0;
        const int s0 = b * SROWS + wid * SROWS_PW;
        #pragma unroll
        for (int i = 0; i < SROWS_PW; ++i) {
            const int s = s0 + i;
            float dot = 0.f;
            if (lane < 50) {
                const float4 e4 = *(const float4*)(enc + (size_t)s * DENC + lane * 4);
                dot = e4.x * v4.x + e4.y * v4.y + e4.z * v4.z + e4.w * v4.w;
            }
            dot = wave_sum(dot);
            if (lane == 0) {
                const double p = exp((double)(dot + c));   // |energy| < ~260 << 709: safe
                p_lds[wid * SROWS_PW + i] = p;
                acc += p;
            }
        }
        if (lane == 0) s_lds[wid] = acc;
    }
    __syncthreads();
    if (t == 0) wsum[b] = s_lds[0] + s_lds[1] + s_lds[2] + s_lds[3];
    grid.sync();

    // ---- Phase 4: global sum (redundant per block), normalize, write ----
    {
        double a = wsum[t] + wsum[t + 256] + wsum[t + 512] + wsum[t + 768];
        a = wave_sum_d(a);
        if (lane == 0) s_lds[wid] = a;
    }
    __syncthreads();
    if (t == 0) inv_lds = 1.0 / (s_lds[0] + s_lds[1] + s_lds[2] + s_lds[3]);
    __syncthreads();

    const double inv = inv_lds;
    if (t < SROWS)
        out[b * SROWS + t] = (float)(p_lds[t] * inv);
}

extern "C" void kernel_launch(void* const* d_in, const int* in_sizes, int n_in,
                              void* d_out, int out_size, void* d_ws, size_t ws_size,
                              hipStream_t stream) {
    const float* hidden = (const float*)d_in[0];   // [H]
    const float* enc    = (const float*)d_in[1];   // [SEQ, DENC]
    const float* W      = (const float*)d_in[2];   // [H, 200]
    const float* bias   = (const float*)d_in[3];   // [H]
    float* out = (float*)d_out;

    double* wsum  = (double*)d_ws;                          // [NBLK]
    float*  vpart = (float*)(wsum + NBLK);                  // [NBLK*DENC]
    float*  cpart = vpart + (size_t)NBLK * DENC;            // [NBLK]
    float*  vfin  = cpart + NBLK;                           // [DENC]
    float*  cfin  = vfin + DENC;                            // [1]

    void* args[] = {(void*)&W, (void*)&hidden, (void*)&bias, (void*)&enc, (void*)&out,
                    (void*)&vpart, (void*)&cpart, (void*)&vfin, (void*)&cfin, (void*)&wsum};
    hipLaunchCooperativeKernel((const void*)fused_attn, dim3(NBLK), dim3(TPB),
                               args, 0, stream);
}

// Round 4
// 74.212 us; speedup vs baseline: 3.8803x; 3.8803x over previous
//
#include <hip/hip_runtime.h>
#include <math.h>

#define SEQ   32768
#define DENC  200
#define NH    8192

#define NBLK  1024
#define TPB   256
#define SROWS 32               // enc rows per block
#define RPW   8                // rows per wave
#define WBLK  256              // blocks that do the W phase
#define WROWS (NH / WBLK)      // 32 W rows per W-block

#define V_SCALE 274877906944.0       // 2^38
#define V_INV   (1.0/274877906944.0)
#define S_SCALE 17179869184.0        // 2^34
#define S_INV   (1.0/17179869184.0)

// ws header: u64 hdr[0..199] = v_acc (s64 fixed-point). Then 16-u64 (128 B)
// slots so every hot atomic lives on its own cacheline.
#define SLOTBASE 208
#define S_CACC  0
#define S_CNTV  1    // ..8   sub-counters for W-phase arrivals (32 each)
#define S_ROOTV 9
#define S_GOV   10   // ..17  go flags for v-ready
#define S_CNT2  18   // ..25  sub-counters for M barrier (128 each)
#define S_ROOT2 26
#define S_GOM   27   // ..34  payload = encoded M key (nonzero when ready)
#define S_MKEY  35   // u32 atomicMax target
#define S_CNT3  36   // ..43  sub-counters for total barrier
#define S_ROOT3 44
#define S_SUBT  45   // ..52  fixed-point partial-sum accumulators
#define S_GOT   53   // ..60  payload = total (u64, nonzero when ready)
#define NSLOT   61
#define HDR_BYTES ((SLOTBASE + 16*NSLOT) * 8)

__device__ __forceinline__ float wave_sum(float x) {
    #pragma unroll
    for (int off = 32; off; off >>= 1) x += __shfl_xor(x, off, 64);
    return x;
}
// monotone float<->uint key for atomicMax (key==0 never produced by real data)
__device__ __forceinline__ unsigned fkey(float f) {
    unsigned b = __float_as_uint(f);
    return (b & 0x80000000u) ? ~b : (b | 0x80000000u);
}
__device__ __forceinline__ float fdec(unsigned k) {
    return __uint_as_float((k & 0x80000000u) ? (k ^ 0x80000000u) : ~k);
}
__device__ __forceinline__ unsigned long long poll_u64(unsigned long long* p) {
    unsigned long long v;
    while ((v = atomicAdd(p, 0ull)) == 0ull) __builtin_amdgcn_s_sleep(8);
    return v;
}
__device__ __forceinline__ unsigned poll_u32(unsigned* p) {
    unsigned v;
    while ((v = atomicAdd(p, 0u)) == 0u) __builtin_amdgcn_s_sleep(8);
    return v;
}

__global__ __launch_bounds__(TPB, 5) void fused_attn(
    const float* __restrict__ W, const float* __restrict__ hidden,
    const float* __restrict__ bias, const float* __restrict__ enc,
    float* __restrict__ out, unsigned long long* __restrict__ hdr)
{
    const int t = threadIdx.x, b = blockIdx.x;
    const int lane = t & 63, wid = t >> 6;
    __shared__ float v_lds[DENC];
    __shared__ float c_lds;
    __shared__ float m_lds[4];
    __shared__ float M_sh, inv_sh;

    unsigned long long* const slot = hdr + SLOTBASE;
    #define SL(i) (slot + 16*(i))

    // ---- P0: preload this wave's 8 enc rows into registers (asm-pinned) ----
    const int s0 = b * SROWS + wid * RPW;
    const bool act = (lane < 50);
    const float* ebase = enc + (size_t)s0 * DENC + lane * 4;
    float4 q0,q1,q2,q3,q4,q5,q6,q7;
    #define LOADQ(i, qi) qi = *(const float4*)(act ? (ebase + (i)*DENC) : enc); \
        asm volatile("" : "+v"(qi.x), "+v"(qi.y), "+v"(qi.z), "+v"(qi.w));
    LOADQ(0,q0) LOADQ(1,q1) LOADQ(2,q2) LOADQ(3,q3)
    LOADQ(4,q4) LOADQ(5,q5) LOADQ(6,q6) LOADQ(7,q7)

    // ---- P1: W phase (blocks 0..WBLK-1): fixed-point atomic v/c accum ----
    if (b < WBLK) {
        const int h0 = b * WROWS;
        if (t < DENC) {
            float acc = 0.f;
            #pragma unroll
            for (int i = 0; i < WROWS; ++i)
                acc = fmaf(W[(size_t)(h0 + i) * DENC + t], hidden[h0 + i], acc);
            const long long q = __double2ll_rn((double)acc * V_SCALE);
            atomicAdd(&hdr[t], (unsigned long long)q);
        }
        if (wid == 0) {
            float cp = (lane < WROWS) ? bias[h0 + lane] * hidden[h0 + lane] : 0.f;
            cp = wave_sum(cp);
            if (lane == 0)
                atomicAdd(SL(S_CACC),
                          (unsigned long long)__double2ll_rn((double)cp * V_SCALE));
        }
        __threadfence();          // each producer drains its own atomics
        __syncthreads();
        if (t == 0) {
            if (atomicAdd(SL(S_CNTV + (b & 7)), 1ull) == (WBLK / 8 - 1)) {
                if (atomicAdd(SL(S_ROOTV), 1ull) == 7ull) {
                    #pragma unroll
                    for (int i = 0; i < 8; ++i) atomicExch(SL(S_GOV + i), 1ull);
                }
            }
        }
    }

    // ---- P2: wait for v ready ----
    if (t == 0) poll_u64(SL(S_GOV + (b & 7)));
    __syncthreads();

    // ---- P3: broadcast v, c into LDS ----
    if (t < DENC)
        v_lds[t] = (float)((double)(long long)hdr[t] * V_INV);
    if (t == DENC)
        c_lds = (float)((double)(long long)(*SL(S_CACC)) * V_INV);
    __syncthreads();

    float4 v4 = make_float4(0.f, 0.f, 0.f, 0.f);
    if (act) v4 = *(const float4*)(v_lds + lane * 4);
    const float c = c_lds;

    // ---- P4: energies (from regs) + global max ----
    float e0,e1,e2,e3,e4,e5,e6,e7;
    #define DOT(qi, ei) { \
        float d = act ? (qi.x*v4.x + qi.y*v4.y + qi.z*v4.z + qi.w*v4.w) : 0.f; \
        ei = wave_sum(d) + c; }
    DOT(q0,e0) DOT(q1,e1) DOT(q2,e2) DOT(q3,e3)
    DOT(q4,e4) DOT(q5,e5) DOT(q6,e6) DOT(q7,e7)

    const float em = fmaxf(fmaxf(fmaxf(e0,e1),fmaxf(e2,e3)),
                           fmaxf(fmaxf(e4,e5),fmaxf(e6,e7)));
    if (lane == 0) m_lds[wid] = em;
    __syncthreads();
    if (t == 0) {
        const float bm = fmaxf(fmaxf(m_lds[0], m_lds[1]),
                               fmaxf(m_lds[2], m_lds[3]));
        atomicMax((unsigned*)SL(S_MKEY), fkey(bm));
        __threadfence();
        if (atomicAdd(SL(S_CNT2 + (b & 7)), 1ull) == (NBLK / 8 - 1)) {
            if (atomicAdd(SL(S_ROOT2), 1ull) == 7ull) {
                const unsigned k = atomicMax((unsigned*)SL(S_MKEY), 0u);
                #pragma unroll
                for (int i = 0; i < 8; ++i)
                    atomicExch((unsigned*)SL(S_GOM + i), k);
            }
        }
    }

    // ---- P5: wait for M ----
    if (t == 0) M_sh = fdec(poll_u32((unsigned*)SL(S_GOM + (b & 7))));
    __syncthreads();
    const float M = M_sh;

    // ---- P6: block exp-sum -> fixed-point atomic total ----
    if (lane == 0) {
        m_lds[wid] = __expf(e0-M)+__expf(e1-M)+__expf(e2-M)+__expf(e3-M)
                   + __expf(e4-M)+__expf(e5-M)+__expf(e6-M)+__expf(e7-M);
    }
    __syncthreads();
    if (t == 0) {
        const float bs = m_lds[0] + m_lds[1] + m_lds[2] + m_lds[3];
        atomicAdd(SL(S_SUBT + (b & 7)),
                  (unsigned long long)__double2ll_rn((double)bs * S_SCALE));
        __threadfence();
        if (atomicAdd(SL(S_CNT3 + (b & 7)), 1ull) == (NBLK / 8 - 1)) {
            if (atomicAdd(SL(S_ROOT3), 1ull) == 7ull) {
                unsigned long long T = 0;
                #pragma unroll
                for (int i = 0; i < 8; ++i) T += atomicAdd(SL(S_SUBT + i), 0ull);
                #pragma unroll
                for (int i = 0; i < 8; ++i) atomicExch(SL(S_GOT + i), T);
            }
        }
    }

    // ---- P7: wait for total ----
    if (t == 0) {
        const unsigned long long T = poll_u64(SL(S_GOT + (b & 7)));
        inv_sh = (float)(1.0 / ((double)(long long)T * S_INV));
    }
    __syncthreads();
    const float inv = inv_sh;

    // ---- P8: write this wave's 8 outputs ----
    if (lane == 0) {
        out[s0+0] = __expf(e0-M)*inv; out[s0+1] = __expf(e1-M)*inv;
        out[s0+2] = __expf(e2-M)*inv; out[s0+3] = __expf(e3-M)*inv;
        out[s0+4] = __expf(e4-M)*inv; out[s0+5] = __expf(e5-M)*inv;
        out[s0+6] = __expf(e6-M)*inv; out[s0+7] = __expf(e7-M)*inv;
    }
}

extern "C" void kernel_launch(void* const* d_in, const int* in_sizes, int n_in,
                              void* d_out, int out_size, void* d_ws, size_t ws_size,
                              hipStream_t stream) {
    const float* hidden = (const float*)d_in[0];   // [H]
    const float* enc    = (const float*)d_in[1];   // [SEQ, DENC]
    const float* W      = (const float*)d_in[2];   // [H, 200]
    const float* bias   = (const float*)d_in[3];   // [H]
    float* out = (float*)d_out;
    unsigned long long* hdr = (unsigned long long*)d_ws;

    hipMemsetAsync(d_ws, 0, HDR_BYTES, stream);
    fused_attn<<<NBLK, TPB, 0, stream>>>(W, hidden, bias, enc, out, hdr);
}